// Round 1
// baseline (2629.888 us; speedup 1.0000x reference)
//
#include <hip/hip_runtime.h>

// RecurrentDecoder: x_proj GEMM -> persistent GRU scan (W_rec in registers,
// device barrier per step) -> dense GEMM to logits. bf16 MFMA, f32 accum.

typedef __attribute__((ext_vector_type(8))) short s16x8;  // 8 bf16 (4 VGPRs)
typedef __attribute__((ext_vector_type(4))) float f32x4;

#define B_      16
#define TSTEPS  255
#define H_      1024
#define G_      3072
#define E_      512
#define V_      32000
#define MROWS   4080   // B_*TSTEPS
#define MPAD    4096
#define NBLK_SCAN 64

__device__ __forceinline__ short f2bf(float f) {   // RNE f32 -> bf16 bits
  unsigned u = __float_as_uint(f);
  u = (u + 0x7fffu + ((u >> 16) & 1u)) >> 16;
  return (short)u;
}

// ---------- prep kernels ----------

// src f32 [K][N] -> dst bf16 [N][K] (so MFMA B-fragments are lane-contiguous)
__global__ void transpose_cvt(const float* __restrict__ src, short* __restrict__ dst,
                              int K, int N) {
  __shared__ float tile[32][33];
  const int n0 = blockIdx.x * 32, k0 = blockIdx.y * 32;
  const int tx = threadIdx.x, ty0 = threadIdx.y;  // (32,8)
#pragma unroll
  for (int yy = 0; yy < 4; ++yy) {
    int ty = ty0 + yy * 8;
    tile[ty][tx] = src[(size_t)(k0 + ty) * N + (n0 + tx)];
  }
  __syncthreads();
#pragma unroll
  for (int yy = 0; yy < 4; ++yy) {
    int ty = ty0 + yy * 8;
    dst[(size_t)(n0 + ty) * K + (k0 + tx)] = f2bf(tile[tx][ty]);
  }
}

// true_outputs (16,256,512) f32 -> teacher A bf16 [4096][512] (rows b*255+t, pad zeroed)
__global__ void pack_teacher(const float* __restrict__ src, short* __restrict__ dst) {
  int idx = blockIdx.x * 256 + threadIdx.x;  // 262144 total
  int row = idx >> 6;
  int c8 = (idx & 63) << 3;
  s16x8 v = {};
  if (row < MROWS) {
    int b = row / TSTEPS, t = row - b * TSTEPS;
    const float* s = src + ((size_t)(b * 256 + t)) * E_ + c8;
#pragma unroll
    for (int j = 0; j < 8; ++j) v[j] = f2bf(s[j]);
  }
  *(s16x8*)(dst + (size_t)row * E_ + c8) = v;
}

__global__ void init_h(const float* __restrict__ latent, short* __restrict__ hbuf) {
  int i = blockIdx.x * 256 + threadIdx.x;  // 16384
  hbuf[i] = f2bf(latent[i]);
}

// ---------- GEMM: C[M][N] = A[M][K](bf16) * BT[N][K](bf16)^T + bias ----------
// 128x128 block, 4 waves each 64x64 (4x4 tiles of 16x16x32), direct global frag loads.
template <bool GUARD>
__global__ __launch_bounds__(256) void gemm_bf16(
    const short* __restrict__ A, const short* __restrict__ BT,
    const float* __restrict__ bias, float* __restrict__ C,
    int Mvalid, int N, int K) {
  const int tid = threadIdx.x;
  const int lane = tid & 63, w = tid >> 6;
  const int r = lane & 15, q = lane >> 4;
  const int bm = blockIdx.y * 128, bn = blockIdx.x * 128;
  const int wm = bm + (w >> 1) * 64, wn = bn + (w & 1) * 64;
  const short* Ab = A + (size_t)(wm + r) * K + q * 8;
  const short* Bb = BT + (size_t)(wn + r) * K + q * 8;
  f32x4 acc[4][4] = {};
  s16x8 a0[4], b0[4], a1[4], b1[4];
  const int nk = K >> 5;
#define GL(AA, BB, kk)                                                         \
  {                                                                            \
    _Pragma("unroll") for (int i = 0; i < 4; ++i) {                            \
      AA[i] = *(const s16x8*)(Ab + (size_t)i * 16 * K + (kk) * 32);            \
    }                                                                          \
    _Pragma("unroll") for (int j = 0; j < 4; ++j) {                            \
      BB[j] = *(const s16x8*)(Bb + (size_t)j * 16 * K + (kk) * 32);            \
    }                                                                          \
  }
#define MM(AA, BB)                                                             \
  {                                                                            \
    _Pragma("unroll") for (int i = 0; i < 4; ++i)                              \
        _Pragma("unroll") for (int j = 0; j < 4; ++j)                          \
            acc[i][j] = __builtin_amdgcn_mfma_f32_16x16x32_bf16(               \
                AA[i], BB[j], acc[i][j], 0, 0, 0);                             \
  }
  GL(a0, b0, 0)
#pragma unroll 1
  for (int ks = 0; ks < nk; ks += 2) {  // nk is even (16 or 32)
    GL(a1, b1, ks + 1)
    MM(a0, b0)
    if (ks + 2 < nk) GL(a0, b0, ks + 2)
    MM(a1, b1)
  }
#undef GL
#undef MM
#pragma unroll
  for (int j = 0; j < 4; ++j) {
    const int col = wn + j * 16 + r;
    const float bv = bias[col];
#pragma unroll
    for (int i = 0; i < 4; ++i) {
#pragma unroll
      for (int rr = 0; rr < 4; ++rr) {
        const int row = wm + i * 16 + q * 4 + rr;
        if (!GUARD || row < Mvalid) C[(size_t)row * N + col] = acc[i][j][rr] + bv;
      }
    }
  }
}

// ---------- persistent GRU scan ----------
// 64 WGs x 256 thr. WG c owns gate columns [16c,16c+16). Wave w covers K range
// [256w,256w+256). W_rec B-fragments live in registers for all 255 steps.
__global__ __launch_bounds__(256) void gru_scan(
    const short* __restrict__ WrecT,   // [3072][1024] bf16
    const float* __restrict__ xproj,   // [4096][3072] f32 (includes bias0)
    const float* __restrict__ bias1,   // recurrent bias [3072]
    const float* __restrict__ latent,  // [16][1024] f32
    short* __restrict__ hbuf,          // [2][16][1024] bf16 ping-pong
    short* __restrict__ gruout,        // [4096][1024] bf16
    unsigned* __restrict__ ctr) {
  const int c = blockIdx.x;
  const int tid = threadIdx.x, lane = tid & 63, w = tid >> 6;
  const int r = lane & 15, q = lane >> 4;
  __shared__ float red[4][3][64][4];

  s16x8 wb[3][8];
#pragma unroll
  for (int g = 0; g < 3; ++g)
#pragma unroll
    for (int s = 0; s < 8; ++s)
      wb[g][s] = *(const s16x8*)(WrecT + (size_t)(g * 1024 + c * 16 + r) * 1024 +
                                 (w * 8 + s) * 32 + q * 8);

  const int m = tid >> 4, nl = tid & 15, col = c * 16 + nl;  // batch, gate col
  float h = latent[m * 1024 + col];
  const float bz = bias1[col], brr = bias1[1024 + col], bhh = bias1[2048 + col];
  const float* xrow = xproj + (size_t)m * TSTEPS * G_;
  short* hb0 = hbuf;
  short* hb1 = hbuf + 16 * 1024;
  float xz = xrow[col], xr = xrow[1024 + col], xh = xrow[2048 + col];

  for (int t = 0; t < TSTEPS; ++t) {
    const short* hcur = (t & 1) ? hb1 : hb0;
    short* hnxt = (t & 1) ? hb0 : hb1;
    s16x8 af[8];
#pragma unroll
    for (int s = 0; s < 8; ++s)
      af[s] = *(const s16x8*)(hcur + r * 1024 + (w * 8 + s) * 32 + q * 8);
    f32x4 acc[3] = {};
#pragma unroll
    for (int s = 0; s < 8; ++s) {
      acc[0] = __builtin_amdgcn_mfma_f32_16x16x32_bf16(af[s], wb[0][s], acc[0], 0, 0, 0);
      acc[1] = __builtin_amdgcn_mfma_f32_16x16x32_bf16(af[s], wb[1][s], acc[1], 0, 0, 0);
      acc[2] = __builtin_amdgcn_mfma_f32_16x16x32_bf16(af[s], wb[2][s], acc[2], 0, 0, 0);
    }
    *(f32x4*)&red[w][0][lane][0] = acc[0];
    *(f32x4*)&red[w][1][lane][0] = acc[1];
    *(f32x4*)&red[w][2][lane][0] = acc[2];
    __syncthreads();
    // reduce 4 K-partials; C-frag mapping col=lane&15, row=(lane>>4)*4+reg
    const int rl = (m >> 2) * 16 + nl, ri = m & 3;
    float rz = bz, rr2 = brr, rh = bhh;
#pragma unroll
    for (int ww = 0; ww < 4; ++ww) {
      rz += red[ww][0][rl][ri];
      rr2 += red[ww][1][rl][ri];
      rh += red[ww][2][rl][ri];
    }
    const float cxz = xz, cxr = xr, cxh = xh;
    {  // prefetch next step's x slice (pad row 4080 exists; never OOB)
      const float* xn = xrow + (size_t)(t + 1) * G_;
      xz = xn[col]; xr = xn[1024 + col]; xh = xn[2048 + col];
    }
    const float z = 1.f / (1.f + __expf(-(cxz + rz)));
    const float rg = 1.f / (1.f + __expf(-(cxr + rr2)));
    const float hh = tanhf(cxh + rg * rh);
    h = z * h + (1.f - z) * hh;     // h stays f32 locally: no bf16 error compounding
    const short hb16 = f2bf(h);
    hnxt[m * 1024 + col] = hb16;
    gruout[((size_t)m * TSTEPS + t) * 1024 + col] = hb16;
    __syncthreads();                 // drains stores (vmcnt0) + LDS WAR
    if (t < TSTEPS - 1) {
      if (tid == 0) {
        __hip_atomic_fetch_add(ctr, 1u, __ATOMIC_RELEASE, __HIP_MEMORY_SCOPE_AGENT);
        const unsigned tgt = (unsigned)NBLK_SCAN * (unsigned)(t + 1);
        while (__hip_atomic_load(ctr, __ATOMIC_ACQUIRE, __HIP_MEMORY_SCOPE_AGENT) < tgt)
          __builtin_amdgcn_s_sleep(2);
      }
      __syncthreads();
    }
  }
}

// ---------- launch ----------
extern "C" void kernel_launch(void* const* d_in, const int* in_sizes, int n_in,
                              void* d_out, int out_size, void* d_ws, size_t ws_size,
                              hipStream_t stream) {
  const float* latent = (const float*)d_in[0];
  const float* trueo  = (const float*)d_in[1];
  const float* gk     = (const float*)d_in[2];
  const float* grk    = (const float*)d_in[3];
  const float* gbias  = (const float*)d_in[4];
  const float* dw     = (const float*)d_in[5];
  const float* db     = (const float*)d_in[6];
  float* out = (float*)d_out;
  char* ws = (char*)d_ws;
  // ws layout (bytes), total ~138.0 MB
  short*    WrecT  = (short*)(ws + 0);          //  6,291,456  [3072][1024] bf16
  short*    GkT    = (short*)(ws + 6291456);    //  3,145,728  [3072][512]  bf16
  short*    DwT    = (short*)(ws + 9437184);    // 65,536,000  [32000][1024] bf16
  short*    teachA = (short*)(ws + 74973184);   //  4,194,304  [4096][512]  bf16
  float*    xproj  = (float*)(ws + 79167488);   // 50,331,648  [4096][3072] f32
  short*    gruout = (short*)(ws + 129499136);  //  8,388,608  [4096][1024] bf16
  short*    hbuf   = (short*)(ws + 137887744);  //     65,536  [2][16][1024] bf16
  unsigned* ctr    = (unsigned*)(ws + 137953280);

  hipMemsetAsync(ctr, 0, 4, stream);
  transpose_cvt<<<dim3(96, 32), dim3(32, 8), 0, stream>>>(grk, WrecT, 1024, 3072);
  transpose_cvt<<<dim3(96, 16), dim3(32, 8), 0, stream>>>(gk, GkT, 512, 3072);
  transpose_cvt<<<dim3(1000, 32), dim3(32, 8), 0, stream>>>(dw, DwT, 1024, 32000);
  pack_teacher<<<1024, 256, 0, stream>>>(trueo, teachA);
  init_h<<<64, 256, 0, stream>>>(latent, hbuf);
  // x_proj = teacher @ gru_kernel + bias0 (store all 4096 padded rows)
  gemm_bf16<false><<<dim3(24, 32), 256, 0, stream>>>(teachA, GkT, gbias, xproj,
                                                     MPAD, G_, E_);
  gru_scan<<<NBLK_SCAN, 256, 0, stream>>>(WrecT, xproj, gbias + G_, latent, hbuf,
                                          gruout, ctr);
  // logits = gru_out @ dense_w + dense_b
  gemm_bf16<true><<<dim3(250, 32), 256, 0, stream>>>(gruout, DwT, db, out,
                                                     MROWS, V_, H_);
}

// Round 2
// 2163.903 us; speedup vs baseline: 1.2153x; 1.2153x over previous
//
#include <hip/hip_runtime.h>

// RecurrentDecoder: x_proj GEMM -> persistent GRU scan (W_rec in registers,
// L3-write-through flag barrier per step) -> dense GEMM to logits.

typedef __attribute__((ext_vector_type(8))) short s16x8;  // 8 bf16 (4 VGPRs)
typedef __attribute__((ext_vector_type(4))) float f32x4;
typedef __attribute__((ext_vector_type(4))) int   i32x4;

#define B_      16
#define TSTEPS  255
#define H_      1024
#define G_      3072
#define E_      512
#define V_      32000
#define MROWS   4080   // B_*TSTEPS
#define MPAD    4096
#define NBLK_SCAN 64

__device__ __forceinline__ short f2bf(float f) {   // RNE f32 -> bf16 bits
  unsigned u = __float_as_uint(f);
  u = (u + 0x7fffu + ((u >> 16) & 1u)) >> 16;
  return (short)u;
}

// 16B load bypassing L1/L2 (sc0 sc1): reads/writes meet at L3 (coherence point)
__device__ __forceinline__ i32x4 ld16_sc(const void* p) {
  i32x4 v;
  asm volatile("global_load_dwordx4 %0, %1, off sc0 sc1" : "=v"(v) : "v"(p) : "memory");
  return v;
}

// ---------- prep kernels ----------

// src f32 [K][N] -> dst bf16 [N][K] (so MFMA B-fragments are lane-contiguous)
__global__ void transpose_cvt(const float* __restrict__ src, short* __restrict__ dst,
                              int K, int N) {
  __shared__ float tile[32][33];
  const int n0 = blockIdx.x * 32, k0 = blockIdx.y * 32;
  const int tx = threadIdx.x, ty0 = threadIdx.y;  // (32,8)
#pragma unroll
  for (int yy = 0; yy < 4; ++yy) {
    int ty = ty0 + yy * 8;
    tile[ty][tx] = src[(size_t)(k0 + ty) * N + (n0 + tx)];
  }
  __syncthreads();
#pragma unroll
  for (int yy = 0; yy < 4; ++yy) {
    int ty = ty0 + yy * 8;
    dst[(size_t)(n0 + ty) * K + (k0 + tx)] = f2bf(tile[tx][ty]);
  }
}

// true_outputs (16,256,512) f32 -> teacher A bf16 [4096][512] (rows b*255+t, pad zeroed)
__global__ void pack_teacher(const float* __restrict__ src, short* __restrict__ dst) {
  int idx = blockIdx.x * 256 + threadIdx.x;  // 262144 total
  int row = idx >> 6;
  int c8 = (idx & 63) << 3;
  s16x8 v = {};
  if (row < MROWS) {
    int b = row / TSTEPS, t = row - b * TSTEPS;
    const float* s = src + ((size_t)(b * 256 + t)) * E_ + c8;
#pragma unroll
    for (int j = 0; j < 8; ++j) v[j] = f2bf(s[j]);
  }
  *(s16x8*)(dst + (size_t)row * E_ + c8) = v;
}

__global__ void init_h(const float* __restrict__ latent, short* __restrict__ hbuf) {
  int i = blockIdx.x * 256 + threadIdx.x;  // 16384
  hbuf[i] = f2bf(latent[i]);
}

// ---------- GEMM: C[M][N] = A[M][K](bf16) * BT[N][K](bf16)^T + bias ----------
// 128x128 block, 4 waves each 64x64 (4x4 tiles of 16x16x32), direct global frag loads.
template <bool GUARD>
__global__ __launch_bounds__(256) void gemm_bf16(
    const short* __restrict__ A, const short* __restrict__ BT,
    const float* __restrict__ bias, float* __restrict__ C,
    int Mvalid, int N, int K) {
  const int tid = threadIdx.x;
  const int lane = tid & 63, w = tid >> 6;
  const int r = lane & 15, q = lane >> 4;
  const int bm = blockIdx.y * 128, bn = blockIdx.x * 128;
  const int wm = bm + (w >> 1) * 64, wn = bn + (w & 1) * 64;
  const short* Ab = A + (size_t)(wm + r) * K + q * 8;
  const short* Bb = BT + (size_t)(wn + r) * K + q * 8;
  f32x4 acc[4][4] = {};
  s16x8 a0[4], b0[4], a1[4], b1[4];
  const int nk = K >> 5;
#define GL(AA, BB, kk)                                                         \
  {                                                                            \
    _Pragma("unroll") for (int i = 0; i < 4; ++i) {                            \
      AA[i] = *(const s16x8*)(Ab + (size_t)i * 16 * K + (kk) * 32);            \
    }                                                                          \
    _Pragma("unroll") for (int j = 0; j < 4; ++j) {                            \
      BB[j] = *(const s16x8*)(Bb + (size_t)j * 16 * K + (kk) * 32);            \
    }                                                                          \
  }
#define MM(AA, BB)                                                             \
  {                                                                            \
    _Pragma("unroll") for (int i = 0; i < 4; ++i)                              \
        _Pragma("unroll") for (int j = 0; j < 4; ++j)                          \
            acc[i][j] = __builtin_amdgcn_mfma_f32_16x16x32_bf16(               \
                AA[i], BB[j], acc[i][j], 0, 0, 0);                             \
  }
  GL(a0, b0, 0)
#pragma unroll 1
  for (int ks = 0; ks < nk; ks += 2) {  // nk is even (16 or 32)
    GL(a1, b1, ks + 1)
    MM(a0, b0)
    if (ks + 2 < nk) GL(a0, b0, ks + 2)
    MM(a1, b1)
  }
#undef GL
#undef MM
#pragma unroll
  for (int j = 0; j < 4; ++j) {
    const int col = wn + j * 16 + r;
    const float bv = bias[col];
#pragma unroll
    for (int i = 0; i < 4; ++i) {
#pragma unroll
      for (int rr = 0; rr < 4; ++rr) {
        const int row = wm + i * 16 + q * 4 + rr;
        if (!GUARD || row < Mvalid) C[(size_t)row * N + col] = acc[i][j][rr] + bv;
      }
    }
  }
}

// ---------- persistent GRU scan ----------
// 64 WGs x 256 thr. WG c owns gate columns [16c,16c+16). Wave w covers K range
// [256w,256w+256). W_rec B-fragments live in registers for all 255 steps.
// Cross-WG sync: write-through (sc0 sc1 / relaxed agent atomics) h exchange at
// L3 + per-WG flag array. No L2 writeback/invalidate, no contended RMW.
__global__ __launch_bounds__(256) void gru_scan(
    const short* __restrict__ WrecT,   // [3072][1024] bf16
    const float* __restrict__ xproj,   // [4096][3072] f32 (includes bias0)
    const float* __restrict__ bias1,   // recurrent bias [3072]
    const float* __restrict__ latent,  // [16][1024] f32
    short* __restrict__ hbuf,          // [2][16][1024] bf16 ping-pong
    short* __restrict__ gruout,        // [4096][1024] bf16
    unsigned* __restrict__ flags) {    // [64], zeroed before launch
  const int c = blockIdx.x;
  const int tid = threadIdx.x, lane = tid & 63, w = tid >> 6;
  const int r = lane & 15, q = lane >> 4;
  __shared__ float red[4][3][64][4];

  s16x8 wb[3][8];
#pragma unroll
  for (int g = 0; g < 3; ++g)
#pragma unroll
    for (int s = 0; s < 8; ++s)
      wb[g][s] = *(const s16x8*)(WrecT + (size_t)(g * 1024 + c * 16 + r) * 1024 +
                                 (w * 8 + s) * 32 + q * 8);

  const int m = tid >> 4, nl = tid & 15, col = c * 16 + nl;  // batch, gate col
  float h = latent[m * 1024 + col];
  const float bz = bias1[col], brr = bias1[1024 + col], bhh = bias1[2048 + col];
  const float* xrow = xproj + (size_t)m * TSTEPS * G_;
  short* hb0 = hbuf;
  short* hb1 = hbuf + 16 * 1024;
  float xz = xrow[col], xr = xrow[1024 + col], xh = xrow[2048 + col];

  for (int t = 0; t < TSTEPS; ++t) {
    const short* hcur = (t & 1) ? hb1 : hb0;
    short* hnxt = (t & 1) ? hb0 : hb1;
    // h broadcast read: bypass L1/L2 (stale ping-pong lines) -> L3 hits
    i32x4 afi[8];
#pragma unroll
    for (int s = 0; s < 8; ++s)
      afi[s] = ld16_sc(hcur + r * 1024 + (w * 8 + s) * 32 + q * 8);
    asm volatile("s_waitcnt vmcnt(0)"
                 : "+v"(afi[0]), "+v"(afi[1]), "+v"(afi[2]), "+v"(afi[3]),
                   "+v"(afi[4]), "+v"(afi[5]), "+v"(afi[6]), "+v"(afi[7])
                 :: "memory");
    f32x4 acc[3] = {};
#pragma unroll
    for (int s = 0; s < 8; ++s) {
      const s16x8 af = *(const s16x8*)&afi[s];
      acc[0] = __builtin_amdgcn_mfma_f32_16x16x32_bf16(af, wb[0][s], acc[0], 0, 0, 0);
      acc[1] = __builtin_amdgcn_mfma_f32_16x16x32_bf16(af, wb[1][s], acc[1], 0, 0, 0);
      acc[2] = __builtin_amdgcn_mfma_f32_16x16x32_bf16(af, wb[2][s], acc[2], 0, 0, 0);
    }
    *(f32x4*)&red[w][0][lane][0] = acc[0];
    *(f32x4*)&red[w][1][lane][0] = acc[1];
    *(f32x4*)&red[w][2][lane][0] = acc[2];
    __syncthreads();
    // reduce 4 K-partials; C-frag mapping col=lane&15, row=(lane>>4)*4+reg
    const int rl = (m >> 2) * 16 + nl, ri = m & 3;
    float rz = bz, rr2 = brr, rh = bhh;
#pragma unroll
    for (int ww = 0; ww < 4; ++ww) {
      rz += red[ww][0][rl][ri];
      rr2 += red[ww][1][rl][ri];
      rh += red[ww][2][rl][ri];
    }
    const float cxz = xz, cxr = xr, cxh = xh;
    {  // prefetch next step's x slice (pad row 4080 exists; never OOB)
      const float* xn = xrow + (size_t)(t + 1) * G_;
      xz = xn[col]; xr = xn[1024 + col]; xh = xn[2048 + col];
    }
    const float z = 1.f / (1.f + __expf(-(cxz + rz)));
    const float rg = 1.f / (1.f + __expf(-(cxr + rr2)));
    const float hh = tanhf(cxh + rg * rh);
    h = z * h + (1.f - z) * hh;     // h stays f32 locally: no bf16 error compounding
    // pack col pairs -> u32; write-through to L3 (relaxed agent atomic store)
    const unsigned hb = (unsigned short)f2bf(h);
    const unsigned nb = __shfl(hb, lane | 1, 64);  // odd neighbor's bits (even lanes)
    const unsigned pv = hb | (nb << 16);
    if (!(tid & 1)) {
      __hip_atomic_store((unsigned*)hnxt + ((m * 1024 + col) >> 1), pv,
                         __ATOMIC_RELAXED, __HIP_MEMORY_SCOPE_AGENT);
      ((unsigned*)gruout)[(((size_t)m * TSTEPS + t) * 1024 + col) >> 1] = pv;
    }
    if (t < TSTEPS - 1) {
      __syncthreads();  // all waves drain vmcnt before barrier -> h stores done
      if (tid == 0)
        __hip_atomic_store(&flags[c], (unsigned)(t + 1),
                           __ATOMIC_RELAXED, __HIP_MEMORY_SCOPE_AGENT);
      // every wave polls all 64 flags (single hop: last writer -> everyone)
      const int fl = tid & 63;
      unsigned v = __hip_atomic_load(&flags[fl], __ATOMIC_RELAXED,
                                     __HIP_MEMORY_SCOPE_AGENT);
      while (!__all(v > (unsigned)t)) {
        __builtin_amdgcn_s_sleep(1);
        v = __hip_atomic_load(&flags[fl], __ATOMIC_RELAXED,
                              __HIP_MEMORY_SCOPE_AGENT);
      }
    }
  }
}

// ---------- launch ----------
extern "C" void kernel_launch(void* const* d_in, const int* in_sizes, int n_in,
                              void* d_out, int out_size, void* d_ws, size_t ws_size,
                              hipStream_t stream) {
  const float* latent = (const float*)d_in[0];
  const float* trueo  = (const float*)d_in[1];
  const float* gk     = (const float*)d_in[2];
  const float* grk    = (const float*)d_in[3];
  const float* gbias  = (const float*)d_in[4];
  const float* dw     = (const float*)d_in[5];
  const float* db     = (const float*)d_in[6];
  float* out = (float*)d_out;
  char* ws = (char*)d_ws;
  // ws layout (bytes), total ~138.0 MB
  short*    WrecT  = (short*)(ws + 0);          //  6,291,456  [3072][1024] bf16
  short*    GkT    = (short*)(ws + 6291456);    //  3,145,728  [3072][512]  bf16
  short*    DwT    = (short*)(ws + 9437184);    // 65,536,000  [32000][1024] bf16
  short*    teachA = (short*)(ws + 74973184);   //  4,194,304  [4096][512]  bf16
  float*    xproj  = (float*)(ws + 79167488);   // 50,331,648  [4096][3072] f32
  short*    gruout = (short*)(ws + 129499136);  //  8,388,608  [4096][1024] bf16
  short*    hbuf   = (short*)(ws + 137887744);  //     65,536  [2][16][1024] bf16
  unsigned* flags  = (unsigned*)(ws + 137953280); //      256  [64]

  hipMemsetAsync(flags, 0, 256, stream);
  transpose_cvt<<<dim3(96, 32), dim3(32, 8), 0, stream>>>(grk, WrecT, 1024, 3072);
  transpose_cvt<<<dim3(96, 16), dim3(32, 8), 0, stream>>>(gk, GkT, 512, 3072);
  transpose_cvt<<<dim3(1000, 32), dim3(32, 8), 0, stream>>>(dw, DwT, 1024, 32000);
  pack_teacher<<<1024, 256, 0, stream>>>(trueo, teachA);
  init_h<<<64, 256, 0, stream>>>(latent, hbuf);
  // x_proj = teacher @ gru_kernel + bias0 (store all 4096 padded rows)
  gemm_bf16<false><<<dim3(24, 32), 256, 0, stream>>>(teachA, GkT, gbias, xproj,
                                                     MPAD, G_, E_);
  gru_scan<<<NBLK_SCAN, 256, 0, stream>>>(WrecT, xproj, gbias + G_, latent, hbuf,
                                          gruout, flags);
  // logits = gru_out @ dense_w + dense_b
  gemm_bf16<true><<<dim3(250, 32), 256, 0, stream>>>(gruout, DwT, db, out,
                                                     MROWS, V_, H_);
}

// Round 3
// 1860.477 us; speedup vs baseline: 1.4136x; 1.1631x over previous
//
#include <hip/hip_runtime.h>

// RecurrentDecoder: x_proj GEMM -> ONE fused persistent kernel:
//   blocks 0..63   = GRU scan (W_rec in registers, L3 flag barrier per step)
//   blocks 64..511 = dense-GEMM workers consuming gruout row-blocks as the
//                    scan publishes progress ([t][m] row layout => smooth
//                    availability). Cross-role coherence via L3 write-through
//                    stores + sc0/sc1 bypass loads (no dispatch boundary).

typedef __attribute__((ext_vector_type(8))) short s16x8;  // 8 bf16 (4 VGPRs)
typedef __attribute__((ext_vector_type(4))) float f32x4;
typedef __attribute__((ext_vector_type(4))) int   i32x4;

#define B_      16
#define TSTEPS  255
#define H_      1024
#define G_      3072
#define E_      512
#define V_      32000
#define MROWS   4080   // B_*TSTEPS
#define MPAD    4096
#define NBLK_SCAN 64
#define NWORK     448
#define NBLK_TOT  512
#define NTILE_RB  32    // 4096/128
#define NTILE_CB  250   // 32000/128

__device__ __forceinline__ short f2bf(float f) {   // RNE f32 -> bf16 bits
  unsigned u = __float_as_uint(f);
  u = (u + 0x7fffu + ((u >> 16) & 1u)) >> 16;
  return (short)u;
}

// 16B load bypassing L1/L2 (sc0 sc1): reads meet write-through stores at L3
#define GLD_SC(dst, p)                                                         \
  asm volatile("global_load_dwordx4 %0, %1, off sc0 sc1"                       \
               : "=v"(dst) : "v"(p) : "memory")
#define GLD(dst, p)                                                            \
  asm volatile("global_load_dwordx4 %0, %1, off"                               \
               : "=v"(dst) : "v"(p) : "memory")

__device__ __forceinline__ i32x4 ld16_sc(const void* p) {
  i32x4 v; GLD_SC(v, p); return v;
}

// ---------- prep kernels ----------

// src f32 [K][N] -> dst bf16 [N][K]
__global__ void transpose_cvt(const float* __restrict__ src, short* __restrict__ dst,
                              int K, int N) {
  __shared__ float tile[32][33];
  const int n0 = blockIdx.x * 32, k0 = blockIdx.y * 32;
  const int tx = threadIdx.x, ty0 = threadIdx.y;  // (32,8)
#pragma unroll
  for (int yy = 0; yy < 4; ++yy) {
    int ty = ty0 + yy * 8;
    tile[ty][tx] = src[(size_t)(k0 + ty) * N + (n0 + tx)];
  }
  __syncthreads();
#pragma unroll
  for (int yy = 0; yy < 4; ++yy) {
    int ty = ty0 + yy * 8;
    dst[(size_t)(n0 + ty) * K + (k0 + tx)] = f2bf(tile[tx][ty]);
  }
}

// true_outputs (16,256,512) f32 -> teacher A bf16 [4096][512], row = t*16+b
__global__ void pack_teacher(const float* __restrict__ src, short* __restrict__ dst) {
  int idx = blockIdx.x * 256 + threadIdx.x;  // 262144 total
  int row = idx >> 6;
  int c8 = (idx & 63) << 3;
  int t = row >> 4, b = row & 15;
  s16x8 v = {};
  if (t < TSTEPS) {
    const float* s = src + ((size_t)(b * 256 + t)) * E_ + c8;
#pragma unroll
    for (int j = 0; j < 8; ++j) v[j] = f2bf(s[j]);
  }
  *(s16x8*)(dst + (size_t)row * E_ + c8) = v;
}

__global__ void init_h(const float* __restrict__ latent, short* __restrict__ hbuf) {
  int i = blockIdx.x * 256 + threadIdx.x;  // 16384
  hbuf[i] = f2bf(latent[i]);
}

// ---------- plain GEMM (xproj only; dispatch-boundary coherence) ----------
__global__ __launch_bounds__(256) void gemm_bf16(
    const short* __restrict__ A, const short* __restrict__ BT,
    const float* __restrict__ bias, float* __restrict__ C, int N, int K) {
  const int tid = threadIdx.x;
  const int lane = tid & 63, w = tid >> 6;
  const int r = lane & 15, q = lane >> 4;
  const int bm = blockIdx.y * 128, bn = blockIdx.x * 128;
  const int wm = bm + (w >> 1) * 64, wn = bn + (w & 1) * 64;
  const short* Ab = A + (size_t)(wm + r) * K + q * 8;
  const short* Bb = BT + (size_t)(wn + r) * K + q * 8;
  f32x4 acc[4][4] = {};
  s16x8 a0[4], b0[4], a1[4], b1[4];
  const int nk = K >> 5;
#define GL(AA, BB, kk)                                                         \
  {                                                                            \
    _Pragma("unroll") for (int i = 0; i < 4; ++i) {                            \
      AA[i] = *(const s16x8*)(Ab + (size_t)i * 16 * K + (kk) * 32);            \
    }                                                                          \
    _Pragma("unroll") for (int j = 0; j < 4; ++j) {                            \
      BB[j] = *(const s16x8*)(Bb + (size_t)j * 16 * K + (kk) * 32);            \
    }                                                                          \
  }
#define MM(AA, BB)                                                             \
  {                                                                            \
    _Pragma("unroll") for (int i = 0; i < 4; ++i)                              \
        _Pragma("unroll") for (int j = 0; j < 4; ++j)                          \
            acc[i][j] = __builtin_amdgcn_mfma_f32_16x16x32_bf16(               \
                AA[i], BB[j], acc[i][j], 0, 0, 0);                             \
  }
  GL(a0, b0, 0)
#pragma unroll 1
  for (int ks = 0; ks < nk; ks += 2) {
    GL(a1, b1, ks + 1)
    MM(a0, b0)
    if (ks + 2 < nk) GL(a0, b0, ks + 2)
    MM(a1, b1)
  }
#undef GL
#pragma unroll
  for (int j = 0; j < 4; ++j) {
    const int col = wn + j * 16 + r;
    const float bv = bias[col];
#pragma unroll
    for (int i = 0; i < 4; ++i) {
#pragma unroll
      for (int rr = 0; rr < 4; ++rr) {
        const int row = wm + i * 16 + q * 4 + rr;
        C[(size_t)row * N + col] = acc[i][j][rr] + bv;
      }
    }
  }
}

// ---------- fused persistent scan + dense GEMM ----------
// sync[0..63] per-scan-WG step flags; sync[64] compacted progress.
__global__ __launch_bounds__(256, 2) void fused_scan_gemm(
    const short* __restrict__ WrecT,   // [3072][1024] bf16
    const float* __restrict__ xproj,   // [4096][3072] f32 rows t*16+m
    const float* __restrict__ bias1,   // recurrent bias [3072]
    const float* __restrict__ latent,  // [16][1024] f32
    short* __restrict__ hbuf,          // [2][16][1024] bf16 ping-pong
    short* __restrict__ gruout,        // [4096][1024] bf16 rows t*16+m
    const short* __restrict__ DwT,     // [32000][1024] bf16
    const float* __restrict__ db,      // [32000]
    float* __restrict__ out,           // [16*255][32000]
    unsigned* __restrict__ sync) {
  const int tid = threadIdx.x, lane = tid & 63, w = tid >> 6;
  const int r = lane & 15, q = lane >> 4;

  if (blockIdx.x < NBLK_SCAN) {
    // ================= scan role =================
    __shared__ float red[4][3][64][4];
    const int c = blockIdx.x;
    s16x8 wb[3][8];
#pragma unroll
    for (int g = 0; g < 3; ++g)
#pragma unroll
      for (int s = 0; s < 8; ++s)
        wb[g][s] = *(const s16x8*)(WrecT + (size_t)(g * 1024 + c * 16 + r) * 1024 +
                                   (w * 8 + s) * 32 + q * 8);

    const int m = tid >> 4, nl = tid & 15, col = c * 16 + nl;
    float h = latent[m * 1024 + col];
    const float bz = bias1[col], brr = bias1[1024 + col], bhh = bias1[2048 + col];
    const float* xb = xproj + (size_t)m * G_;   // row t*16+m => base + t*16*G_
    short* hb0 = hbuf;
    short* hb1 = hbuf + 16 * 1024;
    float xz = xb[col], xr = xb[1024 + col], xh = xb[2048 + col];

    for (int t = 0; t < TSTEPS; ++t) {
      const short* hcur = (t & 1) ? hb1 : hb0;
      short* hnxt = (t & 1) ? hb0 : hb1;
      i32x4 afi[8];
#pragma unroll
      for (int s = 0; s < 8; ++s)
        afi[s] = ld16_sc(hcur + r * 1024 + (w * 8 + s) * 32 + q * 8);
      asm volatile("s_waitcnt vmcnt(0)"
                   : "+v"(afi[0]), "+v"(afi[1]), "+v"(afi[2]), "+v"(afi[3]),
                     "+v"(afi[4]), "+v"(afi[5]), "+v"(afi[6]), "+v"(afi[7])
                   :: "memory");
      __builtin_amdgcn_sched_barrier(0);
      f32x4 acc[3] = {};
#pragma unroll
      for (int s = 0; s < 8; ++s) {
        const s16x8 af = *(const s16x8*)&afi[s];
        acc[0] = __builtin_amdgcn_mfma_f32_16x16x32_bf16(af, wb[0][s], acc[0], 0, 0, 0);
        acc[1] = __builtin_amdgcn_mfma_f32_16x16x32_bf16(af, wb[1][s], acc[1], 0, 0, 0);
        acc[2] = __builtin_amdgcn_mfma_f32_16x16x32_bf16(af, wb[2][s], acc[2], 0, 0, 0);
      }
      *(f32x4*)&red[w][0][lane][0] = acc[0];
      *(f32x4*)&red[w][1][lane][0] = acc[1];
      *(f32x4*)&red[w][2][lane][0] = acc[2];
      __syncthreads();
      const int rl = (m >> 2) * 16 + nl, ri = m & 3;
      float rz = bz, rr2 = brr, rh = bhh;
#pragma unroll
      for (int ww = 0; ww < 4; ++ww) {
        rz += red[ww][0][rl][ri];
        rr2 += red[ww][1][rl][ri];
        rh += red[ww][2][rl][ri];
      }
      const float cxz = xz, cxr = xr, cxh = xh;
      {  // prefetch next step's x slice (row 255*16+m exists, zero-teacher rows)
        const float* xn = xb + (size_t)(t + 1) * 16 * G_;
        xz = xn[col]; xr = xn[1024 + col]; xh = xn[2048 + col];
      }
      const float z = 1.f / (1.f + __expf(-(cxz + rz)));
      const float rg = 1.f / (1.f + __expf(-(cxr + rr2)));
      const float hh = tanhf(cxh + rg * rh);
      h = z * h + (1.f - z) * hh;   // h stays f32 locally
      const unsigned hb = (unsigned short)f2bf(h);
      const unsigned nb = __shfl(hb, lane | 1, 64);
      const unsigned pv = hb | (nb << 16);
      if (!(tid & 1)) {
        __hip_atomic_store((unsigned*)hnxt + ((m * 1024 + col) >> 1), pv,
                           __ATOMIC_RELAXED, __HIP_MEMORY_SCOPE_AGENT);
        // gruout row t*16+m, write-through so workers (other XCDs) see it
        __hip_atomic_store((unsigned*)gruout + (((size_t)(t * 16 + m)) * 1024 + col) / 2,
                           pv, __ATOMIC_RELAXED, __HIP_MEMORY_SCOPE_AGENT);
      }
      __syncthreads();  // drains vmcnt per wave -> all h/gruout stores at L3
      if (tid == 0)
        __hip_atomic_store(&sync[c], (unsigned)(t + 1),
                           __ATOMIC_RELAXED, __HIP_MEMORY_SCOPE_AGENT);
      if (t < TSTEPS - 1 || c == 0) {
        const int fl = tid & 63;
        unsigned v = __hip_atomic_load(&sync[fl], __ATOMIC_RELAXED,
                                       __HIP_MEMORY_SCOPE_AGENT);
        while (!__all(v > (unsigned)t)) {
          __builtin_amdgcn_s_sleep(1);
          v = __hip_atomic_load(&sync[fl], __ATOMIC_RELAXED,
                                __HIP_MEMORY_SCOPE_AGENT);
        }
        if (c == 0 && tid == 0)
          __hip_atomic_store(&sync[64], (unsigned)(t + 1),
                             __ATOMIC_RELAXED, __HIP_MEMORY_SCOPE_AGENT);
      }
    }
  } else {
    // ================= dense GEMM worker role =================
    const int j = blockIdx.x - NBLK_SCAN;  // 0..447
#pragma unroll 1
    for (int tq = j; tq < NTILE_RB * NTILE_CB; tq += NWORK) {
      const int rb = tq / NTILE_CB, cb = tq - rb * NTILE_CB;
      const int t_ready = min(254, rb * 8 + 7);
      const unsigned need = (unsigned)(t_ready + 1);
      unsigned pv = __hip_atomic_load(&sync[64], __ATOMIC_RELAXED,
                                      __HIP_MEMORY_SCOPE_AGENT);
      while (pv < need) {
        __builtin_amdgcn_s_sleep(32);
        pv = __hip_atomic_load(&sync[64], __ATOMIC_RELAXED,
                               __HIP_MEMORY_SCOPE_AGENT);
      }
      const int wm = rb * 128 + (w >> 1) * 64, wn = cb * 128 + (w & 1) * 64;
      const short* Ab = gruout + (size_t)(wm + r) * 1024 + q * 8;
      const short* Bb = DwT + (size_t)(wn + r) * 1024 + q * 8;
      f32x4 acc[4][4] = {};
      i32x4 a0[4], b0[4], a1[4], b1[4];
#define GLT(AA, BB, kk)                                                        \
  {                                                                            \
    _Pragma("unroll") for (int i4 = 0; i4 < 4; ++i4)                           \
        GLD_SC(AA[i4], Ab + (size_t)i4 * 16 * 1024 + (kk) * 32);               \
    _Pragma("unroll") for (int i4 = 0; i4 < 4; ++i4)                           \
        GLD(BB[i4], Bb + (size_t)i4 * 16 * 1024 + (kk) * 32);                  \
  }
#define W8(X, Y)                                                               \
  asm volatile("s_waitcnt vmcnt(8)"                                            \
               : "+v"(X[0]), "+v"(X[1]), "+v"(X[2]), "+v"(X[3]),               \
                 "+v"(Y[0]), "+v"(Y[1]), "+v"(Y[2]), "+v"(Y[3])::"memory");    \
  __builtin_amdgcn_sched_barrier(0);
#define W0(X, Y)                                                               \
  asm volatile("s_waitcnt vmcnt(0)"                                            \
               : "+v"(X[0]), "+v"(X[1]), "+v"(X[2]), "+v"(X[3]),               \
                 "+v"(Y[0]), "+v"(Y[1]), "+v"(Y[2]), "+v"(Y[3])::"memory");    \
  __builtin_amdgcn_sched_barrier(0);
#define MMW(AA, BB)                                                            \
  {                                                                            \
    _Pragma("unroll") for (int i5 = 0; i5 < 4; ++i5)                           \
        _Pragma("unroll") for (int j5 = 0; j5 < 4; ++j5)                       \
            acc[i5][j5] = __builtin_amdgcn_mfma_f32_16x16x32_bf16(             \
                *(const s16x8*)&AA[i5], *(const s16x8*)&BB[j5],                \
                acc[i5][j5], 0, 0, 0);                                         \
  }
      GLT(a0, b0, 0)
#pragma unroll 1
      for (int ks = 0; ks < 30; ks += 2) {
        GLT(a1, b1, ks + 1)
        W8(a0, b0)
        MMW(a0, b0)
        GLT(a0, b0, ks + 2)
        W8(a1, b1)
        MMW(a1, b1)
      }
      GLT(a1, b1, 31)
      W8(a0, b0)
      MMW(a0, b0)
      W0(a1, b1)
      MMW(a1, b1)
#undef GLT
#undef W8
#undef W0
#undef MMW
#pragma unroll
      for (int j2 = 0; j2 < 4; ++j2) {
        const int col = wn + j2 * 16 + r;
        const float bv = db[col];
#pragma unroll
        for (int i = 0; i < 4; ++i) {
#pragma unroll
          for (int rr = 0; rr < 4; ++rr) {
            const int arow = wm + i * 16 + q * 4 + rr;
            const int t = arow >> 4, m = arow & 15;
            if (t < TSTEPS)
              out[(size_t)(m * TSTEPS + t) * V_ + col] = acc[i][j2][rr] + bv;
          }
        }
      }
    }
  }
}

// ---------- launch ----------
extern "C" void kernel_launch(void* const* d_in, const int* in_sizes, int n_in,
                              void* d_out, int out_size, void* d_ws, size_t ws_size,
                              hipStream_t stream) {
  const float* latent = (const float*)d_in[0];
  const float* trueo  = (const float*)d_in[1];
  const float* gk     = (const float*)d_in[2];
  const float* grk    = (const float*)d_in[3];
  const float* gbias  = (const float*)d_in[4];
  const float* dw     = (const float*)d_in[5];
  const float* db     = (const float*)d_in[6];
  float* out = (float*)d_out;
  char* ws = (char*)d_ws;
  short*    WrecT  = (short*)(ws + 0);          //  6,291,456  [3072][1024] bf16
  short*    GkT    = (short*)(ws + 6291456);    //  3,145,728  [3072][512]  bf16
  short*    DwT    = (short*)(ws + 9437184);    // 65,536,000  [32000][1024] bf16
  short*    teachA = (short*)(ws + 74973184);   //  4,194,304  [4096][512]  bf16 rows t*16+b
  float*    xproj  = (float*)(ws + 79167488);   // 50,331,648  [4096][3072] f32 rows t*16+m
  short*    gruout = (short*)(ws + 129499136);  //  8,388,608  [4096][1024] bf16 rows t*16+m
  short*    hbuf   = (short*)(ws + 137887744);  //     65,536  [2][16][1024] bf16
  unsigned* syncb  = (unsigned*)(ws + 137953280); //     512   flags[64] + progress

  hipMemsetAsync(syncb, 0, 512, stream);
  transpose_cvt<<<dim3(96, 32), dim3(32, 8), 0, stream>>>(grk, WrecT, 1024, 3072);
  transpose_cvt<<<dim3(96, 16), dim3(32, 8), 0, stream>>>(gk, GkT, 512, 3072);
  transpose_cvt<<<dim3(1000, 32), dim3(32, 8), 0, stream>>>(dw, DwT, 1024, 32000);
  pack_teacher<<<1024, 256, 0, stream>>>(trueo, teachA);
  init_h<<<64, 256, 0, stream>>>(latent, hbuf);
  gemm_bf16<<<dim3(24, 32), 256, 0, stream>>>(teachA, GkT, gbias, xproj, G_, E_);
  fused_scan_gemm<<<NBLK_TOT, 256, 0, stream>>>(WrecT, xproj, gbias + G_, latent,
                                                hbuf, gruout, DwT, db, out, syncb);
}

// Round 4
// 1313.772 us; speedup vs baseline: 2.0018x; 1.4161x over previous
//
#include <hip/hip_runtime.h>

// RecurrentDecoder: x_proj GEMM -> ONE fused persistent kernel:
//   blocks 0..63   = GRU scan (W_rec in registers, L3 flag barrier per step,
//                    setprio(3), gruout/xproj traffic off the critical path)
//   blocks 64..511 = dense-GEMM workers; A (gruout) read with NORMAL cached
//                    loads (lines written-through once, first touch after
//                    write => coherent), B (DwT) cached. vmcnt-pipelined.

typedef __attribute__((ext_vector_type(8))) short s16x8;  // 8 bf16 (4 VGPRs)
typedef __attribute__((ext_vector_type(4))) float f32x4;
typedef __attribute__((ext_vector_type(4))) int   i32x4;

#define B_      16
#define TSTEPS  255
#define H_      1024
#define G_      3072
#define E_      512
#define V_      32000
#define MROWS   4080   // B_*TSTEPS
#define MPAD    4096
#define NBLK_SCAN 64
#define NWORK     448
#define NBLK_TOT  512
#define NTILE_RB  32    // 4096/128
#define NTILE_CB  250   // 32000/128
#define FSTRIDE   16    // flags padded to 64B (one L3-visible line each)
#define PROG_IDX  1024  // progress dword index in sync buffer

__device__ __forceinline__ short f2bf(float f) {   // RNE f32 -> bf16 bits
  unsigned u = __float_as_uint(f);
  u = (u + 0x7fffu + ((u >> 16) & 1u)) >> 16;
  return (short)u;
}

__device__ __forceinline__ float frcp(float x) {  // v_rcp_f32 (~1ulp, fine for bf16)
  float r;
  asm("v_rcp_f32 %0, %1" : "=v"(r) : "v"(x));
  return r;
}

// 16B load bypassing L1/L2 (sc0 sc1): reads meet write-through stores at L3
#define GLD_SC(dst, p)                                                         \
  asm volatile("global_load_dwordx4 %0, %1, off sc0 sc1"                       \
               : "=v"(dst) : "v"(p) : "memory")
#define GLD(dst, p)                                                            \
  asm volatile("global_load_dwordx4 %0, %1, off"                               \
               : "=v"(dst) : "v"(p) : "memory")

__device__ __forceinline__ i32x4 ld16_sc(const void* p) {
  i32x4 v; GLD_SC(v, p); return v;
}

// ---------- prep kernels ----------

// src f32 [K][N] -> dst bf16 [N][K]
__global__ void transpose_cvt(const float* __restrict__ src, short* __restrict__ dst,
                              int K, int N) {
  __shared__ float tile[32][33];
  const int n0 = blockIdx.x * 32, k0 = blockIdx.y * 32;
  const int tx = threadIdx.x, ty0 = threadIdx.y;  // (32,8)
#pragma unroll
  for (int yy = 0; yy < 4; ++yy) {
    int ty = ty0 + yy * 8;
    tile[ty][tx] = src[(size_t)(k0 + ty) * N + (n0 + tx)];
  }
  __syncthreads();
#pragma unroll
  for (int yy = 0; yy < 4; ++yy) {
    int ty = ty0 + yy * 8;
    dst[(size_t)(n0 + ty) * K + (k0 + tx)] = f2bf(tile[tx][ty]);
  }
}

// true_outputs (16,256,512) f32 -> teacher A bf16 [4096][512], row = t*16+b
__global__ void pack_teacher(const float* __restrict__ src, short* __restrict__ dst) {
  int idx = blockIdx.x * 256 + threadIdx.x;  // 262144 total
  int row = idx >> 6;
  int c8 = (idx & 63) << 3;
  int t = row >> 4, b = row & 15;
  s16x8 v = {};
  if (t < TSTEPS) {
    const float* s = src + ((size_t)(b * 256 + t)) * E_ + c8;
#pragma unroll
    for (int j = 0; j < 8; ++j) v[j] = f2bf(s[j]);
  }
  *(s16x8*)(dst + (size_t)row * E_ + c8) = v;
}

__global__ void init_h(const float* __restrict__ latent, short* __restrict__ hbuf) {
  int i = blockIdx.x * 256 + threadIdx.x;  // 16384
  hbuf[i] = f2bf(latent[i]);
}

// ---------- plain GEMM (xproj only; dispatch-boundary coherence) ----------
__global__ __launch_bounds__(256) void gemm_bf16(
    const short* __restrict__ A, const short* __restrict__ BT,
    const float* __restrict__ bias, float* __restrict__ C, int N, int K) {
  const int tid = threadIdx.x;
  const int lane = tid & 63, w = tid >> 6;
  const int r = lane & 15, q = lane >> 4;
  const int bm = blockIdx.y * 128, bn = blockIdx.x * 128;
  const int wm = bm + (w >> 1) * 64, wn = bn + (w & 1) * 64;
  const short* Ab = A + (size_t)(wm + r) * K + q * 8;
  const short* Bb = BT + (size_t)(wn + r) * K + q * 8;
  f32x4 acc[4][4] = {};
  s16x8 a0[4], b0[4], a1[4], b1[4];
  const int nk = K >> 5;
#define GL(AA, BB, kk)                                                         \
  {                                                                            \
    _Pragma("unroll") for (int i = 0; i < 4; ++i) {                            \
      AA[i] = *(const s16x8*)(Ab + (size_t)i * 16 * K + (kk) * 32);            \
    }                                                                          \
    _Pragma("unroll") for (int j = 0; j < 4; ++j) {                            \
      BB[j] = *(const s16x8*)(Bb + (size_t)j * 16 * K + (kk) * 32);            \
    }                                                                          \
  }
#define MM(AA, BB)                                                             \
  {                                                                            \
    _Pragma("unroll") for (int i = 0; i < 4; ++i)                              \
        _Pragma("unroll") for (int j = 0; j < 4; ++j)                          \
            acc[i][j] = __builtin_amdgcn_mfma_f32_16x16x32_bf16(               \
                AA[i], BB[j], acc[i][j], 0, 0, 0);                             \
  }
  GL(a0, b0, 0)
#pragma unroll 1
  for (int ks = 0; ks < nk; ks += 2) {
    GL(a1, b1, ks + 1)
    MM(a0, b0)
    if (ks + 2 < nk) GL(a0, b0, ks + 2)
    MM(a1, b1)
  }
#undef GL
#pragma unroll
  for (int j = 0; j < 4; ++j) {
    const int col = wn + j * 16 + r;
    const float bv = bias[col];
#pragma unroll
    for (int i = 0; i < 4; ++i) {
#pragma unroll
      for (int rr = 0; rr < 4; ++rr) {
        const int row = wm + i * 16 + q * 4 + rr;
        C[(size_t)row * N + col] = acc[i][j][rr] + bv;
      }
    }
  }
}

// ---------- fused persistent scan + dense GEMM ----------
// sync[c*16] per-scan-WG step flags (64B apart); sync[1024] compacted progress.
// Flag semantics: flag[c] == f  =>  h(f) visible at L3 AND gruout(f-2) visible.
__global__ __launch_bounds__(256, 2) void fused_scan_gemm(
    const short* __restrict__ WrecT,   // [3072][1024] bf16
    const float* __restrict__ xproj,   // [4096][3072] f32 rows t*16+m
    const float* __restrict__ bias1,   // recurrent bias [3072]
    const float* __restrict__ latent,  // [16][1024] f32
    short* __restrict__ hbuf,          // [2][16][1024] bf16 ping-pong
    short* __restrict__ gruout,        // [4096][1024] bf16 rows t*16+m
    const short* __restrict__ DwT,     // [32000][1024] bf16
    const float* __restrict__ db,      // [32000]
    float* __restrict__ out,           // [16*255][32000]
    unsigned* __restrict__ sync) {
  const int tid = threadIdx.x, lane = tid & 63, w = tid >> 6;
  const int r = lane & 15, q = lane >> 4;

  if (blockIdx.x < NBLK_SCAN) {
    // ================= scan role =================
    __builtin_amdgcn_s_setprio(3);   // shield serial critical path from workers
    __shared__ float red[4][3][64][4];
    const int c = blockIdx.x;
    s16x8 wb[3][8];
#pragma unroll
    for (int g = 0; g < 3; ++g)
#pragma unroll
      for (int s = 0; s < 8; ++s)
        wb[g][s] = *(const s16x8*)(WrecT + (size_t)(g * 1024 + c * 16 + r) * 1024 +
                                   (w * 8 + s) * 32 + q * 8);

    const int m = tid >> 4, nl = tid & 15, col = c * 16 + nl;
    float h = latent[m * 1024 + col];
    const float bz = bias1[col], brr = bias1[1024 + col], bhh = bias1[2048 + col];
    const float* xb = xproj + (size_t)m * G_;   // row t*16+m => base + t*16*G_
    short* hb0 = hbuf;
    short* hb1 = hbuf + 16 * 1024;
    float xz = xb[col], xr = xb[1024 + col], xh = xb[2048 + col];

    for (int t = 0; t < TSTEPS; ++t) {
      const short* hcur = (t & 1) ? hb1 : hb0;
      short* hnxt = (t & 1) ? hb0 : hb1;
      i32x4 afi[8];
#pragma unroll
      for (int s = 0; s < 8; ++s)
        afi[s] = ld16_sc(hcur + r * 1024 + (w * 8 + s) * 32 + q * 8);
      asm volatile("s_waitcnt vmcnt(0)"
                   : "+v"(afi[0]), "+v"(afi[1]), "+v"(afi[2]), "+v"(afi[3]),
                     "+v"(afi[4]), "+v"(afi[5]), "+v"(afi[6]), "+v"(afi[7])
                   :: "memory");
      __builtin_amdgcn_sched_barrier(0);
      f32x4 acc[3] = {};
#pragma unroll
      for (int s = 0; s < 8; ++s) {
        const s16x8 af = *(const s16x8*)&afi[s];
        acc[0] = __builtin_amdgcn_mfma_f32_16x16x32_bf16(af, wb[0][s], acc[0], 0, 0, 0);
        acc[1] = __builtin_amdgcn_mfma_f32_16x16x32_bf16(af, wb[1][s], acc[1], 0, 0, 0);
        acc[2] = __builtin_amdgcn_mfma_f32_16x16x32_bf16(af, wb[2][s], acc[2], 0, 0, 0);
      }
      *(f32x4*)&red[w][0][lane][0] = acc[0];
      *(f32x4*)&red[w][1][lane][0] = acc[1];
      *(f32x4*)&red[w][2][lane][0] = acc[2];
      __syncthreads();  // also drains prev-step gruout + xproj prefetch (hidden)
      const int rl = (m >> 2) * 16 + nl, ri = m & 3;
      float rz = bz, rr2 = brr, rh = bhh;
#pragma unroll
      for (int ww = 0; ww < 4; ++ww) {
        rz += red[ww][0][rl][ri];
        rr2 += red[ww][1][rl][ri];
        rh += red[ww][2][rl][ri];
      }
      const float z = frcp(1.f + __expf(-(xz + rz)));
      const float rg = frcp(1.f + __expf(-(xr + rr2)));
      const float hh = tanhf(xh + rg * rh);
      h = z * h + (1.f - z) * hh;   // h stays f32 locally
      const unsigned hb = (unsigned short)f2bf(h);
      const unsigned nb = __shfl(hb, lane | 1, 64);
      const unsigned pv = hb | (nb << 16);
      if (!(tid & 1))
        __hip_atomic_store((unsigned*)hnxt + ((m * 1024 + col) >> 1), pv,
                           __ATOMIC_RELAXED, __HIP_MEMORY_SCOPE_AGENT);
      __syncthreads();  // drains ONLY the h stores -> short L3 ack
      if (tid == 0)
        __hip_atomic_store(&sync[c * FSTRIDE], (unsigned)(t + 1),
                           __ATOMIC_RELAXED, __HIP_MEMORY_SCOPE_AGENT);
      // ---- off-critical-path traffic: drains during poll / next step ----
      if (!(tid & 1))
        __hip_atomic_store((unsigned*)gruout + (((size_t)(t * 16 + m)) * 1024 + col) / 2,
                           pv, __ATOMIC_RELAXED, __HIP_MEMORY_SCOPE_AGENT);
      {  // prefetch next step's x slice (row 255*16+m exists: zero-teacher rows)
        const float* xn = xb + (size_t)(t + 1) * 16 * G_;
        xz = xn[col]; xr = xn[1024 + col]; xh = xn[2048 + col];
      }
      if (t < TSTEPS - 1) {
        const int fl = lane;
        unsigned v = __hip_atomic_load(&sync[fl * FSTRIDE], __ATOMIC_RELAXED,
                                       __HIP_MEMORY_SCOPE_AGENT);
        while (!__all(v > (unsigned)t)) {
          __builtin_amdgcn_s_sleep(1);
          v = __hip_atomic_load(&sync[fl * FSTRIDE], __ATOMIC_RELAXED,
                                __HIP_MEMORY_SCOPE_AGENT);
        }
        if (c == 0 && tid == 0)
          __hip_atomic_store(&sync[PROG_IDX], (unsigned)(t + 1),
                             __ATOMIC_RELAXED, __HIP_MEMORY_SCOPE_AGENT);
      }
    }
    // epilogue: make final gruout rows visible, then flags -> 256
    asm volatile("s_waitcnt vmcnt(0)" ::: "memory");
    __syncthreads();
    if (tid == 0)
      __hip_atomic_store(&sync[c * FSTRIDE], 256u,
                         __ATOMIC_RELAXED, __HIP_MEMORY_SCOPE_AGENT);
    if (c == 0) {
      unsigned v = __hip_atomic_load(&sync[lane * FSTRIDE], __ATOMIC_RELAXED,
                                     __HIP_MEMORY_SCOPE_AGENT);
      while (!__all(v >= 256u)) {
        __builtin_amdgcn_s_sleep(1);
        v = __hip_atomic_load(&sync[lane * FSTRIDE], __ATOMIC_RELAXED,
                              __HIP_MEMORY_SCOPE_AGENT);
      }
      if (tid == 0)
        __hip_atomic_store(&sync[PROG_IDX], 256u,
                           __ATOMIC_RELAXED, __HIP_MEMORY_SCOPE_AGENT);
    }
  } else {
    // ================= dense GEMM worker role =================
    const int j = blockIdx.x - NBLK_SCAN;  // 0..447
#pragma unroll 1
    for (int tq = j; tq < NTILE_RB * NTILE_CB; tq += NWORK) {
      const int rb = tq / NTILE_CB, cb = tq - rb * NTILE_CB;
      // progress >= t_ready+2 guarantees gruout rows of this rb visible at L3
      const unsigned need = (unsigned)(min(254, rb * 8 + 7) + 2);
      unsigned pv = __hip_atomic_load(&sync[PROG_IDX], __ATOMIC_RELAXED,
                                      __HIP_MEMORY_SCOPE_AGENT);
      while (pv < need) {
        __builtin_amdgcn_s_sleep(32);
        pv = __hip_atomic_load(&sync[PROG_IDX], __ATOMIC_RELAXED,
                               __HIP_MEMORY_SCOPE_AGENT);
      }
      const int wm = rb * 128 + (w >> 1) * 64, wn = cb * 128 + (w & 1) * 64;
      // A via NORMAL cached loads: gruout lines written-through to L3 once,
      // never in any L2 before first read (dispatch-start invalidate) => the
      // L2 miss fetches fresh data; later reads are L2 hits.
      const short* Ab = gruout + (size_t)(wm + r) * 1024 + q * 8;
      const short* Bb = DwT + (size_t)(wn + r) * 1024 + q * 8;
      f32x4 acc[4][4] = {};
      i32x4 a0[4], b0[4], a1[4], b1[4];
#define GLT(AA, BB, kk)                                                        \
  {                                                                            \
    _Pragma("unroll") for (int i4 = 0; i4 < 4; ++i4)                           \
        GLD(AA[i4], Ab + (size_t)i4 * 16 * 1024 + (kk) * 32);                  \
    _Pragma("unroll") for (int i4 = 0; i4 < 4; ++i4)                           \
        GLD(BB[i4], Bb + (size_t)i4 * 16 * 1024 + (kk) * 32);                  \
  }
#define W8(X, Y)                                                               \
  asm volatile("s_waitcnt vmcnt(8)"                                            \
               : "+v"(X[0]), "+v"(X[1]), "+v"(X[2]), "+v"(X[3]),               \
                 "+v"(Y[0]), "+v"(Y[1]), "+v"(Y[2]), "+v"(Y[3])::"memory");    \
  __builtin_amdgcn_sched_barrier(0);
#define W0(X, Y)                                                               \
  asm volatile("s_waitcnt vmcnt(0)"                                            \
               : "+v"(X[0]), "+v"(X[1]), "+v"(X[2]), "+v"(X[3]),               \
                 "+v"(Y[0]), "+v"(Y[1]), "+v"(Y[2]), "+v"(Y[3])::"memory");    \
  __builtin_amdgcn_sched_barrier(0);
#define MMW(AA, BB)                                                            \
  {                                                                            \
    _Pragma("unroll") for (int i5 = 0; i5 < 4; ++i5)                           \
        _Pragma("unroll") for (int j5 = 0; j5 < 4; ++j5)                       \
            acc[i5][j5] = __builtin_amdgcn_mfma_f32_16x16x32_bf16(             \
                *(const s16x8*)&AA[i5], *(const s16x8*)&BB[j5],                \
                acc[i5][j5], 0, 0, 0);                                         \
  }
      GLT(a0, b0, 0)
#pragma unroll 1
      for (int ks = 0; ks < 30; ks += 2) {
        GLT(a1, b1, ks + 1)
        W8(a0, b0)
        MMW(a0, b0)
        GLT(a0, b0, ks + 2)
        W8(a1, b1)
        MMW(a1, b1)
      }
      GLT(a1, b1, 31)
      W8(a0, b0)
      MMW(a0, b0)
      W0(a1, b1)
      MMW(a1, b1)
#undef GLT
#undef W8
#undef W0
#undef MMW
#pragma unroll
      for (int j2 = 0; j2 < 4; ++j2) {
        const int col = wn + j2 * 16 + r;
        const float bv = db[col];
#pragma unroll
        for (int i = 0; i < 4; ++i) {
#pragma unroll
          for (int rr = 0; rr < 4; ++rr) {
            const int arow = wm + i * 16 + q * 4 + rr;
            const int t = arow >> 4, mm = arow & 15;
            if (t < TSTEPS)
              out[(size_t)(mm * TSTEPS + t) * V_ + col] = acc[i][j2][rr] + bv;
          }
        }
      }
    }
  }
}

// ---------- launch ----------
extern "C" void kernel_launch(void* const* d_in, const int* in_sizes, int n_in,
                              void* d_out, int out_size, void* d_ws, size_t ws_size,
                              hipStream_t stream) {
  const float* latent = (const float*)d_in[0];
  const float* trueo  = (const float*)d_in[1];
  const float* gk     = (const float*)d_in[2];
  const float* grk    = (const float*)d_in[3];
  const float* gbias  = (const float*)d_in[4];
  const float* dw     = (const float*)d_in[5];
  const float* db     = (const float*)d_in[6];
  float* out = (float*)d_out;
  char* ws = (char*)d_ws;
  short*    WrecT  = (short*)(ws + 0);          //  6,291,456  [3072][1024] bf16
  short*    GkT    = (short*)(ws + 6291456);    //  3,145,728  [3072][512]  bf16
  short*    DwT    = (short*)(ws + 9437184);    // 65,536,000  [32000][1024] bf16
  short*    teachA = (short*)(ws + 74973184);   //  4,194,304  [4096][512]  bf16 rows t*16+b
  float*    xproj  = (float*)(ws + 79167488);   // 50,331,648  [4096][3072] f32 rows t*16+m
  short*    gruout = (short*)(ws + 129499136);  //  8,388,608  [4096][1024] bf16 rows t*16+m
  short*    hbuf   = (short*)(ws + 137887744);  //     65,536  [2][16][1024] bf16
  unsigned* syncb  = (unsigned*)(ws + 137953280); //    8,192  flags[64*16] + progress

  hipMemsetAsync(syncb, 0, 8192, stream);
  transpose_cvt<<<dim3(96, 32), dim3(32, 8), 0, stream>>>(grk, WrecT, 1024, 3072);
  transpose_cvt<<<dim3(96, 16), dim3(32, 8), 0, stream>>>(gk, GkT, 512, 3072);
  transpose_cvt<<<dim3(1000, 32), dim3(32, 8), 0, stream>>>(dw, DwT, 1024, 32000);
  pack_teacher<<<1024, 256, 0, stream>>>(trueo, teachA);
  init_h<<<64, 256, 0, stream>>>(latent, hbuf);
  gemm_bf16<<<dim3(24, 32), 256, 0, stream>>>(teachA, GkT, gbias, xproj, G_, E_);
  fused_scan_gemm<<<NBLK_TOT, 256, 0, stream>>>(WrecT, xproj, gbias + G_, latent,
                                                hbuf, gruout, DwT, db, out, syncb);
}

// Round 5
// 971.341 us; speedup vs baseline: 2.7075x; 1.3525x over previous
//
#include <hip/hip_runtime.h>

// RecurrentDecoder: x_proj GEMM -> ONE fused persistent kernel:
//   blocks 0..63   = GRU scan (W_rec in registers, L3 flag barrier per step,
//                    setprio(3), gruout/xproj traffic off the critical path)
//   blocks 64..511 = dense-GEMM workers, m97-style LDS double-buffered
//                    pipeline (global_load_lds dwordx4, 1 barrier/K-step),
//                    nt stores for logits (keep DwT resident in L3).

typedef __attribute__((ext_vector_type(8))) short s16x8;  // 8 bf16 (4 VGPRs)
typedef __attribute__((ext_vector_type(4))) float f32x4;
typedef __attribute__((ext_vector_type(4))) int   i32x4;

#define B_      16
#define TSTEPS  255
#define H_      1024
#define G_      3072
#define E_      512
#define V_      32000
#define MROWS   4080   // B_*TSTEPS
#define MPAD    4096
#define NBLK_SCAN 64
#define NWORK     448
#define NBLK_TOT  512
#define NTILE_RB  32    // 4096/128
#define NTILE_CB  250   // 32000/128
#define FSTRIDE   16    // flags padded to 64B (one L3-visible line each)
#define PROG_IDX  1024  // progress dword index in sync buffer

__device__ __forceinline__ short f2bf(float f) {   // RNE f32 -> bf16 bits
  unsigned u = __float_as_uint(f);
  u = (u + 0x7fffu + ((u >> 16) & 1u)) >> 16;
  return (short)u;
}

__device__ __forceinline__ float frcp(float x) {  // v_rcp_f32 (~1ulp, fine for bf16)
  float r;
  asm("v_rcp_f32 %0, %1" : "=v"(r) : "v"(x));
  return r;
}

// 16B load bypassing L1/L2 (sc0 sc1): reads meet write-through stores at L3
__device__ __forceinline__ i32x4 ld16_sc(const void* p) {
  i32x4 v;
  asm volatile("global_load_dwordx4 %0, %1, off sc0 sc1" : "=v"(v) : "v"(p) : "memory");
  return v;
}

// async global->LDS 16B: HW writes lane l at (wave-uniform) ldsbase + l*16
__device__ __forceinline__ void gload_lds16(const short* g, void* l) {
  __builtin_amdgcn_global_load_lds((const __attribute__((address_space(1))) void*)g,
                                   (__attribute__((address_space(3))) void*)l,
                                   16, 0, 0);
}

// ---------- prep kernels ----------

// src f32 [K][N] -> dst bf16 [N][K]
__global__ void transpose_cvt(const float* __restrict__ src, short* __restrict__ dst,
                              int K, int N) {
  __shared__ float tile[32][33];
  const int n0 = blockIdx.x * 32, k0 = blockIdx.y * 32;
  const int tx = threadIdx.x, ty0 = threadIdx.y;  // (32,8)
#pragma unroll
  for (int yy = 0; yy < 4; ++yy) {
    int ty = ty0 + yy * 8;
    tile[ty][tx] = src[(size_t)(k0 + ty) * N + (n0 + tx)];
  }
  __syncthreads();
#pragma unroll
  for (int yy = 0; yy < 4; ++yy) {
    int ty = ty0 + yy * 8;
    dst[(size_t)(n0 + ty) * K + (k0 + tx)] = f2bf(tile[tx][ty]);
  }
}

// true_outputs (16,256,512) f32 -> teacher A bf16 [4096][512], row = t*16+b
__global__ void pack_teacher(const float* __restrict__ src, short* __restrict__ dst) {
  int idx = blockIdx.x * 256 + threadIdx.x;  // 262144 total
  int row = idx >> 6;
  int c8 = (idx & 63) << 3;
  int t = row >> 4, b = row & 15;
  s16x8 v = {};
  if (t < TSTEPS) {
    const float* s = src + ((size_t)(b * 256 + t)) * E_ + c8;
#pragma unroll
    for (int j = 0; j < 8; ++j) v[j] = f2bf(s[j]);
  }
  *(s16x8*)(dst + (size_t)row * E_ + c8) = v;
}

__global__ void init_h(const float* __restrict__ latent, short* __restrict__ hbuf) {
  int i = blockIdx.x * 256 + threadIdx.x;  // 16384
  hbuf[i] = f2bf(latent[i]);
}

// ---------- plain GEMM (xproj only; dispatch-boundary coherence) ----------
__global__ __launch_bounds__(256) void gemm_bf16(
    const short* __restrict__ A, const short* __restrict__ BT,
    const float* __restrict__ bias, float* __restrict__ C, int N, int K) {
  const int tid = threadIdx.x;
  const int lane = tid & 63, w = tid >> 6;
  const int r = lane & 15, q = lane >> 4;
  const int bm = blockIdx.y * 128, bn = blockIdx.x * 128;
  const int wm = bm + (w >> 1) * 64, wn = bn + (w & 1) * 64;
  const short* Ab = A + (size_t)(wm + r) * K + q * 8;
  const short* Bb = BT + (size_t)(wn + r) * K + q * 8;
  f32x4 acc[4][4] = {};
  s16x8 a0[4], b0[4], a1[4], b1[4];
  const int nk = K >> 5;
#define GL(AA, BB, kk)                                                         \
  {                                                                            \
    _Pragma("unroll") for (int i = 0; i < 4; ++i) {                            \
      AA[i] = *(const s16x8*)(Ab + (size_t)i * 16 * K + (kk) * 32);            \
    }                                                                          \
    _Pragma("unroll") for (int j = 0; j < 4; ++j) {                            \
      BB[j] = *(const s16x8*)(Bb + (size_t)j * 16 * K + (kk) * 32);            \
    }                                                                          \
  }
#define MM(AA, BB)                                                             \
  {                                                                            \
    _Pragma("unroll") for (int i = 0; i < 4; ++i)                              \
        _Pragma("unroll") for (int j = 0; j < 4; ++j)                          \
            acc[i][j] = __builtin_amdgcn_mfma_f32_16x16x32_bf16(               \
                AA[i], BB[j], acc[i][j], 0, 0, 0);                             \
  }
  GL(a0, b0, 0)
#pragma unroll 1
  for (int ks = 0; ks < nk; ks += 2) {
    GL(a1, b1, ks + 1)
    MM(a0, b0)
    if (ks + 2 < nk) GL(a0, b0, ks + 2)
    MM(a1, b1)
  }
#undef GL
#undef MM
#pragma unroll
  for (int j = 0; j < 4; ++j) {
    const int col = wn + j * 16 + r;
    const float bv = bias[col];
#pragma unroll
    for (int i = 0; i < 4; ++i) {
#pragma unroll
      for (int rr = 0; rr < 4; ++rr) {
        const int row = wm + i * 16 + q * 4 + rr;
        C[(size_t)row * N + col] = acc[i][j][rr] + bv;
      }
    }
  }
}

// ---------- fused persistent scan + dense GEMM ----------
// sync[c*16] per-scan-WG step flags (64B apart); sync[1024] compacted progress.
__global__ __launch_bounds__(256, 2) void fused_scan_gemm(
    const short* __restrict__ WrecT,   // [3072][1024] bf16
    const float* __restrict__ xproj,   // [4096][3072] f32 rows t*16+m
    const float* __restrict__ bias1,   // recurrent bias [3072]
    const float* __restrict__ latent,  // [16][1024] f32
    short* __restrict__ hbuf,          // [2][16][1024] bf16 ping-pong
    short* __restrict__ gruout,        // [4096][1024] bf16 rows t*16+m
    const short* __restrict__ DwT,     // [32000][1024] bf16
    const float* __restrict__ db,      // [32000]
    float* __restrict__ out,           // [16*255][32000]
    unsigned* __restrict__ sync) {
  const int tid = threadIdx.x, lane = tid & 63, w = tid >> 6;
  const int r = lane & 15, q = lane >> 4;
  __shared__ s16x8 smem_v[2048];       // 32 KiB, shared between roles

  if (blockIdx.x < NBLK_SCAN) {
    // ================= scan role (unchanged from R4) =================
    __builtin_amdgcn_s_setprio(3);   // shield serial critical path from workers
    float (*red)[3][64][4] = (float(*)[3][64][4])smem_v;
    const int c = blockIdx.x;
    s16x8 wb[3][8];
#pragma unroll
    for (int g = 0; g < 3; ++g)
#pragma unroll
      for (int s = 0; s < 8; ++s)
        wb[g][s] = *(const s16x8*)(WrecT + (size_t)(g * 1024 + c * 16 + r) * 1024 +
                                   (w * 8 + s) * 32 + q * 8);

    const int m = tid >> 4, nl = tid & 15, col = c * 16 + nl;
    float h = latent[m * 1024 + col];
    const float bz = bias1[col], brr = bias1[1024 + col], bhh = bias1[2048 + col];
    const float* xb = xproj + (size_t)m * G_;   // row t*16+m => base + t*16*G_
    short* hb0 = hbuf;
    short* hb1 = hbuf + 16 * 1024;
    float xz = xb[col], xr = xb[1024 + col], xh = xb[2048 + col];

    for (int t = 0; t < TSTEPS; ++t) {
      const short* hcur = (t & 1) ? hb1 : hb0;
      short* hnxt = (t & 1) ? hb0 : hb1;
      i32x4 afi[8];
#pragma unroll
      for (int s = 0; s < 8; ++s)
        afi[s] = ld16_sc(hcur + r * 1024 + (w * 8 + s) * 32 + q * 8);
      asm volatile("s_waitcnt vmcnt(0)"
                   : "+v"(afi[0]), "+v"(afi[1]), "+v"(afi[2]), "+v"(afi[3]),
                     "+v"(afi[4]), "+v"(afi[5]), "+v"(afi[6]), "+v"(afi[7])
                   :: "memory");
      __builtin_amdgcn_sched_barrier(0);
      f32x4 acc[3] = {};
#pragma unroll
      for (int s = 0; s < 8; ++s) {
        const s16x8 af = *(const s16x8*)&afi[s];
        acc[0] = __builtin_amdgcn_mfma_f32_16x16x32_bf16(af, wb[0][s], acc[0], 0, 0, 0);
        acc[1] = __builtin_amdgcn_mfma_f32_16x16x32_bf16(af, wb[1][s], acc[1], 0, 0, 0);
        acc[2] = __builtin_amdgcn_mfma_f32_16x16x32_bf16(af, wb[2][s], acc[2], 0, 0, 0);
      }
      *(f32x4*)&red[w][0][lane][0] = acc[0];
      *(f32x4*)&red[w][1][lane][0] = acc[1];
      *(f32x4*)&red[w][2][lane][0] = acc[2];
      __syncthreads();  // also drains prev-step gruout + xproj prefetch (hidden)
      const int rl = (m >> 2) * 16 + nl, ri = m & 3;
      float rz = bz, rr2 = brr, rh = bhh;
#pragma unroll
      for (int ww = 0; ww < 4; ++ww) {
        rz += red[ww][0][rl][ri];
        rr2 += red[ww][1][rl][ri];
        rh += red[ww][2][rl][ri];
      }
      const float z = frcp(1.f + __expf(-(xz + rz)));
      const float rg = frcp(1.f + __expf(-(xr + rr2)));
      const float hh = tanhf(xh + rg * rh);
      h = z * h + (1.f - z) * hh;   // h stays f32 locally
      const unsigned hb = (unsigned short)f2bf(h);
      const unsigned nb = __shfl(hb, lane | 1, 64);
      const unsigned pv = hb | (nb << 16);
      if (!(tid & 1))
        __hip_atomic_store((unsigned*)hnxt + ((m * 1024 + col) >> 1), pv,
                           __ATOMIC_RELAXED, __HIP_MEMORY_SCOPE_AGENT);
      __syncthreads();  // drains ONLY the h stores -> short L3 ack
      if (tid == 0)
        __hip_atomic_store(&sync[c * FSTRIDE], (unsigned)(t + 1),
                           __ATOMIC_RELAXED, __HIP_MEMORY_SCOPE_AGENT);
      // ---- off-critical-path traffic: drains during poll / next step ----
      if (!(tid & 1))
        __hip_atomic_store((unsigned*)gruout + (((size_t)(t * 16 + m)) * 1024 + col) / 2,
                           pv, __ATOMIC_RELAXED, __HIP_MEMORY_SCOPE_AGENT);
      {  // prefetch next step's x slice (row 255*16+m exists: zero-teacher rows)
        const float* xn = xb + (size_t)(t + 1) * 16 * G_;
        xz = xn[col]; xr = xn[1024 + col]; xh = xn[2048 + col];
      }
      if (t < TSTEPS - 1) {
        const int fl = lane;
        unsigned v = __hip_atomic_load(&sync[fl * FSTRIDE], __ATOMIC_RELAXED,
                                       __HIP_MEMORY_SCOPE_AGENT);
        while (!__all(v > (unsigned)t)) {
          __builtin_amdgcn_s_sleep(1);
          v = __hip_atomic_load(&sync[fl * FSTRIDE], __ATOMIC_RELAXED,
                                __HIP_MEMORY_SCOPE_AGENT);
        }
        if (c == 0 && tid == 0)
          __hip_atomic_store(&sync[PROG_IDX], (unsigned)(t + 1),
                             __ATOMIC_RELAXED, __HIP_MEMORY_SCOPE_AGENT);
      }
    }
    // epilogue: make final gruout rows visible, then flags -> 256
    asm volatile("s_waitcnt vmcnt(0)" ::: "memory");
    __syncthreads();
    if (tid == 0)
      __hip_atomic_store(&sync[c * FSTRIDE], 256u,
                         __ATOMIC_RELAXED, __HIP_MEMORY_SCOPE_AGENT);
    if (c == 0) {
      unsigned v = __hip_atomic_load(&sync[lane * FSTRIDE], __ATOMIC_RELAXED,
                                     __HIP_MEMORY_SCOPE_AGENT);
      while (!__all(v >= 256u)) {
        __builtin_amdgcn_s_sleep(1);
        v = __hip_atomic_load(&sync[lane * FSTRIDE], __ATOMIC_RELAXED,
                              __HIP_MEMORY_SCOPE_AGENT);
      }
      if (tid == 0)
        __hip_atomic_store(&sync[PROG_IDX], 256u,
                           __ATOMIC_RELAXED, __HIP_MEMORY_SCOPE_AGENT);
    }
  } else {
    // ================= dense GEMM worker role (m97 LDS pipeline) =========
    // LDS: buf{0,1} x (A[128][32] | B[128][32]) bf16 = 2 x 16 KiB.
    char* sb = (char*)smem_v;
    const int wr = w >> 1, wc = w & 1;
    const int j = blockIdx.x - NBLK_SCAN;  // 0..447
#pragma unroll 1
    for (int tq = j; tq < NTILE_RB * NTILE_CB; tq += NWORK) {
      const int rb = tq / NTILE_CB, cb = tq - rb * NTILE_CB;
      // progress >= t_ready+2 guarantees gruout rows of this rb visible at L3
      const unsigned need = (unsigned)(min(254, rb * 8 + 7) + 2);
      unsigned pv = __hip_atomic_load(&sync[PROG_IDX], __ATOMIC_RELAXED,
                                      __HIP_MEMORY_SCOPE_AGENT);
      while (pv < need) {
        __builtin_amdgcn_s_sleep(32);
        pv = __hip_atomic_load(&sync[PROG_IDX], __ATOMIC_RELAXED,
                               __HIP_MEMORY_SCOPE_AGENT);
      }
      const short* Ag = gruout + (size_t)rb * 128 * 1024;  // cached: coherent
      const short* Bg = DwT + (size_t)cb * 128 * 1024;
      f32x4 acc[4][4] = {};
      // stage K-step kk into buf: lane l writes ldsbase + l*16 (linear layout)
#define STAGE(buf, kk)                                                         \
  {                                                                            \
    _Pragma("unroll") for (int it = 0; it < 2; ++it) {                         \
      const size_t go = (size_t)(w * 32 + it * 16 + (lane >> 2)) * 1024 +      \
                        (kk) * 32 + (lane & 3) * 8;                            \
      char* lb = sb + (buf) * 16384 + w * 2048 + it * 1024;                    \
      gload_lds16(Ag + go, lb);                                                \
      gload_lds16(Bg + go, lb + 8192);                                         \
    }                                                                          \
  }
      STAGE(0, 0)
#pragma unroll 1
      for (int kk = 0; kk < 32; ++kk) {
        __syncthreads();             // staged kk visible; prev buf reads done
        if (kk < 31) STAGE((kk + 1) & 1, kk + 1)
        const char* ab = sb + (kk & 1) * 16384;
        s16x8 af[4], bf[4];
#pragma unroll
        for (int i = 0; i < 4; ++i)
          af[i] = *(const s16x8*)(ab + (wr * 64 + i * 16 + r) * 64 + q * 16);
#pragma unroll
        for (int j5 = 0; j5 < 4; ++j5)
          bf[j5] = *(const s16x8*)(ab + 8192 + (wc * 64 + j5 * 16 + r) * 64 + q * 16);
#pragma unroll
        for (int i = 0; i < 4; ++i)
#pragma unroll
          for (int j5 = 0; j5 < 4; ++j5)
            acc[i][j5] = __builtin_amdgcn_mfma_f32_16x16x32_bf16(
                af[i], bf[j5], acc[i][j5], 0, 0, 0);
      }
#undef STAGE
      const int wm = rb * 128 + wr * 64, wn = cb * 128 + wc * 64;
#pragma unroll
      for (int j2 = 0; j2 < 4; ++j2) {
        const int col = wn + j2 * 16 + r;
        const float bv = db[col];
#pragma unroll
        for (int i = 0; i < 4; ++i) {
#pragma unroll
          for (int rr = 0; rr < 4; ++rr) {
            const int arow = wm + i * 16 + q * 4 + rr;
            const int t = arow >> 4, mm = arow & 15;
            if (t < TSTEPS)
              __builtin_nontemporal_store(
                  acc[i][j2][rr] + bv,
                  &out[(size_t)(mm * TSTEPS + t) * V_ + col]);
          }
        }
      }
      __syncthreads();  // LDS WAR: next tile's STAGE(0,0) vs this tile's reads
    }
  }
}

// ---------- launch ----------
extern "C" void kernel_launch(void* const* d_in, const int* in_sizes, int n_in,
                              void* d_out, int out_size, void* d_ws, size_t ws_size,
                              hipStream_t stream) {
  const float* latent = (const float*)d_in[0];
  const float* trueo  = (const float*)d_in[1];
  const float* gk     = (const float*)d_in[2];
  const float* grk    = (const float*)d_in[3];
  const float* gbias  = (const float*)d_in[4];
  const float* dw     = (const float*)d_in[5];
  const float* db     = (const float*)d_in[6];
  float* out = (float*)d_out;
  char* ws = (char*)d_ws;
  short*    WrecT  = (short*)(ws + 0);          //  6,291,456  [3072][1024] bf16
  short*    GkT    = (short*)(ws + 6291456);    //  3,145,728  [3072][512]  bf16
  short*    DwT    = (short*)(ws + 9437184);    // 65,536,000  [32000][1024] bf16
  short*    teachA = (short*)(ws + 74973184);   //  4,194,304  [4096][512]  bf16 rows t*16+b
  float*    xproj  = (float*)(ws + 79167488);   // 50,331,648  [4096][3072] f32 rows t*16+m
  short*    gruout = (short*)(ws + 129499136);  //  8,388,608  [4096][1024] bf16 rows t*16+m
  short*    hbuf   = (short*)(ws + 137887744);  //     65,536  [2][16][1024] bf16
  unsigned* syncb  = (unsigned*)(ws + 137953280); //    8,192  flags[64*16] + progress

  hipMemsetAsync(syncb, 0, 8192, stream);
  transpose_cvt<<<dim3(96, 32), dim3(32, 8), 0, stream>>>(grk, WrecT, 1024, 3072);
  transpose_cvt<<<dim3(96, 16), dim3(32, 8), 0, stream>>>(gk, GkT, 512, 3072);
  transpose_cvt<<<dim3(1000, 32), dim3(32, 8), 0, stream>>>(dw, DwT, 1024, 32000);
  pack_teacher<<<1024, 256, 0, stream>>>(trueo, teachA);
  init_h<<<64, 256, 0, stream>>>(latent, hbuf);
  gemm_bf16<<<dim3(24, 32), 256, 0, stream>>>(teachA, GkT, gbias, xproj, G_, E_);
  fused_scan_gemm<<<NBLK_TOT, 256, 0, stream>>>(WrecT, xproj, gbias + G_, latent,
                                                hbuf, gruout, DwT, db, out, syncb);
}